// Round 6
// baseline (58.396 us; speedup 1.0000x reference)
//
#include <hip/hip_runtime.h>
#include <hip/hip_bf16.h>

#define HW 9216
#define CDIM 128
#define BM 256                      // rows per block (8 waves x 32 rows)
#define BN 64                       // cols per tile
#define JT 4                        // tiles per block -> 256 cols/block
#define GRID_I (HW / BM)            // 36
#define GRID_J (HW / (BN * JT))     // 36
#define NPART (GRID_I * GRID_J)     // 1296 partial pairs
#define LDP (CDIM + 8)              // padded LDS stride (272B)
#define SCH (HW / 512)              // 18 elements per sort thread

using bf16 = __hip_bfloat16;
typedef __attribute__((ext_vector_type(16))) float f32x16;
typedef __attribute__((ext_vector_type(8))) short s16x8;

// exp(d/0.04) = exp2(d * log2(e)/0.04); scale folded into feat1 at prep time
#define EXP_SCALE 36.067376022224085f

#if __has_builtin(__builtin_amdgcn_exp2f)
#define FEXP2(x) __builtin_amdgcn_exp2f(x)
#else
#define FEXP2(x) exp2f(x)
#endif

// ---------------------------------------------------------------------------
// Kernel 0: deterministic stable 3-bucket sort of each side's labels.
// perm[side][sortedPos] = original index; labs[side][sortedPos] = label.
// grid = 2 blocks (one per side) x 512 threads, 18 elems/thread.
// ---------------------------------------------------------------------------
__global__ __launch_bounds__(512) void sort_kernel(const int* __restrict__ label,
                                                   int* __restrict__ perm,
                                                   int* __restrict__ labs) {
    const int side = blockIdx.x;
    const int* L = label + side * HW;
    int* P = perm + side * HW;
    int* S = labs + side * HW;
    __shared__ int cnt[3][512];

    int t = threadIdx.x;
    int l[SCH];
    int c0 = 0, c1 = 0, c2 = 0;
#pragma unroll
    for (int k = 0; k < SCH; ++k) {
        l[k] = L[t * SCH + k];
        c0 += (l[k] == 0); c1 += (l[k] == 1); c2 += (l[k] == 2);
    }
    cnt[0][t] = c0; cnt[1][t] = c1; cnt[2][t] = c2;
    __syncthreads();

    // Hillis-Steele inclusive scan over 512 entries, 3 labels together
    for (int off = 1; off < 512; off <<= 1) {
        int v0 = cnt[0][t], v1 = cnt[1][t], v2 = cnt[2][t];
        int a0 = 0, a1 = 0, a2 = 0;
        if (t >= off) { a0 = cnt[0][t - off]; a1 = cnt[1][t - off]; a2 = cnt[2][t - off]; }
        __syncthreads();
        cnt[0][t] = v0 + a0; cnt[1][t] = v1 + a1; cnt[2][t] = v2 + a2;
        __syncthreads();
    }

    int i0 = cnt[0][t], i1 = cnt[1][t], i2 = cnt[2][t];   // inclusive prefix
    int tl0 = cnt[0][511], tl1 = cnt[1][511];             // bucket totals
    int o0 = i0 - c0;
    int o1 = tl0 + i1 - c1;
    int o2 = tl0 + tl1 + i2 - c2;
#pragma unroll
    for (int k = 0; k < SCH; ++k) {
        int lab = l[k];
        int pos = (lab == 0) ? o0++ : ((lab == 1) ? o1++ : o2++);
        P[pos] = t * SCH + k;
        S[pos] = lab;
    }
}

// ---------------------------------------------------------------------------
// Kernel 1: x[b] [C][HW] f32 -> feat[b] [sortedRow][C] bf16 via perm gather.
// feat1 pre-scaled by EXP_SCALE. grid=(HW/64, C/64, 2), block=256.
// ---------------------------------------------------------------------------
__global__ __launch_bounds__(256) void prep_kernel(const float* __restrict__ x,
                                                   const int* __restrict__ perm,
                                                   bf16* __restrict__ feat) {
    __shared__ float tile[64][65];
    const float* xs = x + (size_t)blockIdx.z * CDIM * HW;
    const int* permS = perm + blockIdx.z * HW;
    bf16* fs = feat + (size_t)blockIdx.z * HW * CDIM;
    float scale = (blockIdx.z == 0) ? EXP_SCALE : 1.0f;

    int p0 = blockIdx.x * 64;
    int c0 = blockIdx.y * 64;
    int t  = threadIdx.x;

    int pc = t & 63;
    int cr = t >> 6;
    int pidx = permS[p0 + pc];          // gathered source position (reused x16)
#pragma unroll
    for (int i = 0; i < 16; ++i) {
        int cl = cr + i * 4;
        tile[cl][pc] = xs[(size_t)(c0 + cl) * HW + pidx];
    }
    __syncthreads();

    int cc = t & 63;
    int pr = t >> 6;
#pragma unroll
    for (int i = 0; i < 16; ++i) {
        int pl = pr + i * 4;
        fs[(size_t)(p0 + pl) * CDIM + c0 + cc] = __float2bfloat16(tile[cc][pl] * scale);
    }
}

// ---------------------------------------------------------------------------
// Kernel 2: 256-row band x 256 cols per block, 8 waves x 32 rows, sorted rows.
// mfma_f32_32x32x16_bf16; A frags register-resident; B tiles double-buffered
// in LDS (T14 async stage, raw barriers). Sorted labels make almost every
// 32x32 fragment mask-uniform: epilogue = exp + packed sum + 1 fma/fragment.
// grid = (36, 36), block = 512. One partial pair per block.
// ---------------------------------------------------------------------------
__global__ __launch_bounds__(512, 4) void simsum_kernel(const bf16* __restrict__ feat1,
                                                        const bf16* __restrict__ feat2,
                                                        const int* __restrict__ labs,
                                                        float* __restrict__ partials) {
    __shared__ bf16 Bs[2][BN][LDP];
    __shared__ float red[16];

    const int* lab1s = labs;            // sorted row labels
    const int* lab2s = labs + HW;       // sorted col labels

    int t    = threadIdx.x;
    int w    = t >> 6;           // wave 0..7
    int lane = t & 63;
    int cl   = lane & 31;        // row/col lane index within fragment
    int hi   = lane >> 5;        // k-half select

    int i0  = blockIdx.x * BM;
    int jb  = blockIdx.y * (BN * JT);
    int r0w = i0 + w * 32;       // this wave's 32 output rows (sorted)

    // A fragments (pre-scaled feat1): lane row = cl, k = s*16 + hi*8
    s16x8 af[8];
    {
        const bf16* arow = &feat1[(size_t)(r0w + cl) * CDIM + hi * 8];
#pragma unroll
        for (int s = 0; s < 8; ++s)
            af[s] = *(const s16x8*)(arow + s * 16);
    }

    // sorted-row uniformity for this wave (monotone labels: endpoints suffice)
    int rlab  = lab1s[r0w];
    bool rowU = (rlab == lab1s[r0w + 31]);

    // fallback row labels: C row = (reg&3) + 8*(reg>>2) + 4*hi
    int4 g1i[4];
#pragma unroll
    for (int q = 0; q < 4; ++q)
        g1i[q] = *(const int4*)(&lab1s[r0w + 4 * hi + 8 * q]);

    // staging: tile = 64 rows x 256B; thread covers rows srow, srow+32
    int srow = t >> 4;           // 0..31
    int sch8 = (t & 15) * 8;     // bf16 col offset
    s16x8 rb[2];

    auto load_tile = [&](int tt) {
        const bf16* base = &feat2[(size_t)(jb + tt * BN + srow) * CDIM + sch8];
        rb[0] = *(const s16x8*)(base);
        rb[1] = *(const s16x8*)(base + 32 * CDIM);
    };
    auto write_tile = [&](int b) {
        *(s16x8*)(&Bs[b][srow][sch8])      = rb[0];
        *(s16x8*)(&Bs[b][srow + 32][sch8]) = rb[1];
    };

    load_tile(0);  write_tile(0);
    load_tile(1);  write_tile(1);
    load_tile(2);
    asm volatile("s_waitcnt lgkmcnt(0)" ::: "memory");
    __builtin_amdgcn_sched_barrier(0);
    __builtin_amdgcn_s_barrier();

    float tot0 = 0.f, tot1 = 0.f, pos0 = 0.f, pos1 = 0.f;

#pragma unroll
    for (int tt = 0; tt < JT; ++tt) {
        int cb = jb + tt * BN;
        // chain label info (L1-broadcast loads)
        int laA = lab2s[cb];
        int laB = lab2s[cb + 32];
        bool uniA = rowU && (laA == lab2s[cb + 31]);
        bool uniB = rowU && (laB == lab2s[cb + 63]);
        int g2a = lab2s[cb + cl];        // per-lane (fallback only)
        int g2b = lab2s[cb + 32 + cl];

        // MFMA: 2 independent 32x32 acc chains over 8 k-steps
        f32x16 acc0 = {}, acc1 = {};
        __builtin_amdgcn_s_setprio(1);
#pragma unroll
        for (int s = 0; s < 8; ++s) {
            const bf16* bp = &Bs[tt & 1][cl][s * 16 + hi * 8];
            s16x8 b0 = *(const s16x8*)(bp);
            s16x8 b1 = *(const s16x8*)(bp + (size_t)32 * LDP);
            acc0 = __builtin_amdgcn_mfma_f32_32x32x16_bf16(af[s], b0, acc0, 0, 0, 0);
            acc1 = __builtin_amdgcn_mfma_f32_32x32x16_bf16(af[s], b1, acc1, 0, 0, 0);
        }
        __builtin_amdgcn_s_setprio(0);

        __builtin_amdgcn_sched_barrier(0);
        __builtin_amdgcn_s_barrier();    // all waves done reading Bs[tt&1]

        // T14: commit prefetched tile tt+2 into freed buffer; issue tt+3 loads
        if (tt + 2 < JT) write_tile(tt & 1);
        if (tt + 3 < JT) load_tile(tt + 3);

        // epilogue: exp + fragment sums; mask applied per fragment (uniform)
        {
            float a0 = 0.f, a1 = 0.f, a2 = 0.f, a3 = 0.f;
            float b0 = 0.f, b1 = 0.f, b2 = 0.f, b3 = 0.f;
#pragma unroll
            for (int r = 0; r < 4; ++r) {
                a0 += FEXP2(acc0[r]);
                a1 += FEXP2(acc0[r + 4]);
                a2 += FEXP2(acc0[r + 8]);
                a3 += FEXP2(acc0[r + 12]);
                b0 += FEXP2(acc1[r]);
                b1 += FEXP2(acc1[r + 4]);
                b2 += FEXP2(acc1[r + 8]);
                b3 += FEXP2(acc1[r + 12]);
            }
            float csA = (a0 + a1) + (a2 + a3);
            float csB = (b0 + b1) + (b2 + b3);
            tot0 += csA;
            tot1 += csB;
            if (uniA) {
                pos0 += (rlab == laA) ? csA : 0.f;
            } else {
#pragma unroll
                for (int r = 0; r < 16; ++r) {
                    int g1 = ((const int*)g1i)[r];
                    pos0 += (g1 == g2a) ? FEXP2(acc0[r]) : 0.f;
                }
            }
            if (uniB) {
                pos1 += (rlab == laB) ? csB : 0.f;
            } else {
#pragma unroll
                for (int r = 0; r < 16; ++r) {
                    int g1 = ((const int*)g1i)[r];
                    pos1 += (g1 == g2b) ? FEXP2(acc1[r]) : 0.f;
                }
            }
        }

        if (tt + 1 < JT) {
            asm volatile("s_waitcnt lgkmcnt(0)" ::: "memory");   // ds_writes done
            __builtin_amdgcn_sched_barrier(0);
            __builtin_amdgcn_s_barrier(); // next buffer fully written by all
        }
    }

    float tot = tot0 + tot1, pos = pos0 + pos1;
#pragma unroll
    for (int off = 32; off; off >>= 1) {
        tot += __shfl_down(tot, off);
        pos += __shfl_down(pos, off);
    }
    if (lane == 0) { red[w * 2] = tot; red[w * 2 + 1] = pos; }
    __syncthreads();
    if (t == 0) {
        float T = 0.f, P = 0.f;
#pragma unroll
        for (int q = 0; q < 8; ++q) { T += red[q * 2]; P += red[q * 2 + 1]; }
        int bid = blockIdx.y * GRID_I + blockIdx.x;
        partials[bid * 2]     = T;
        partials[bid * 2 + 1] = P;
    }
}

// ---------------------------------------------------------------------------
// Kernel 3: reduce partial pairs, loss = -log(pos/tot)/hw^2
// ---------------------------------------------------------------------------
__global__ __launch_bounds__(256) void finalize_kernel(const float* __restrict__ partials,
                                                       float* __restrict__ out) {
    double tot = 0.0, pos = 0.0;
    int t = threadIdx.x;
    for (int i = t; i < NPART; i += 256) {
        tot += (double)partials[i * 2];
        pos += (double)partials[i * 2 + 1];
    }
#pragma unroll
    for (int off = 32; off; off >>= 1) {
        tot += __shfl_down(tot, off);
        pos += __shfl_down(pos, off);
    }
    __shared__ double rt[4], rp[4];
    int w = t >> 6, lane = t & 63;
    if (lane == 0) { rt[w] = tot; rp[w] = pos; }
    __syncthreads();
    if (t == 0) {
        double T = rt[0] + rt[1] + rt[2] + rt[3];
        double P = rp[0] + rp[1] + rp[2] + rp[3];
        double hw2 = (double)HW * (double)HW;
        out[0] = (float)(-log(P / T) / hw2);
    }
}

extern "C" void kernel_launch(void* const* d_in, const int* in_sizes, int n_in,
                              void* d_out, int out_size, void* d_ws, size_t ws_size,
                              hipStream_t stream) {
    const float* x     = (const float*)d_in[0];   // (4,128,96,96) f32; only b=0,1 used
    const int*   label = (const int*)d_in[1];     // (4,1,96,96) i32; only b=0,1 used
    float*       out   = (float*)d_out;

    bf16* feat = (bf16*)d_ws;                     // feat1 (pre-scaled), feat2
    char* pp   = (char*)d_ws + 2 * (size_t)HW * CDIM * sizeof(bf16);
    int*  perm = (int*)pp;                        // [2][HW]
    int*  labs = (int*)(pp + 2 * (size_t)HW * sizeof(int));   // [2][HW]
    float* parts = (float*)(pp + 4 * (size_t)HW * sizeof(int));

    sort_kernel<<<2, 512, 0, stream>>>(label, perm, labs);

    dim3 g1(HW / 64, CDIM / 64, 2);
    prep_kernel<<<g1, 256, 0, stream>>>(x, perm, feat);

    dim3 g2(GRID_I, GRID_J);
    simsum_kernel<<<g2, 512, 0, stream>>>(feat, feat + (size_t)HW * CDIM, labs, parts);

    finalize_kernel<<<1, 256, 0, stream>>>(parts, out);
}